// Round 1
// 1067.207 us; speedup vs baseline: 1.1128x; 1.1128x over previous
//
#include <hip/hip_runtime.h>
#include <stdint.h>

#define T_TOKENS 8192
#define DDIM 2048
#define FDIM 4096
#define NEXP 8
#define MAXT1 40   // 256-row tiles (gemm1): max 32+7 < 40
#define MAXT2 72   // 128-row tiles (gemm2): max 64+7 < 72

typedef __attribute__((ext_vector_type(8))) short bf16x8;
typedef __attribute__((ext_vector_type(4))) float f32x4;

// round-to-nearest-even fp32 -> bf16 (finite inputs)
__device__ __forceinline__ unsigned short f2bf(float f) {
  unsigned int u = __float_as_uint(f);
  unsigned int r = (u + 0x7FFFu + ((u >> 16) & 1u)) >> 16;
  return (unsigned short)r;
}

__global__ void k_assign(const float* __restrict__ logits,
                         int* __restrict__ assign,
                         int* __restrict__ counts) {
  int t = blockIdx.x * blockDim.x + threadIdx.x;
  if (t >= T_TOKENS) return;
  const float* l = logits + (size_t)t * NEXP;
  float bv = l[0]; int be = 0;
#pragma unroll
  for (int e = 1; e < NEXP; ++e) {
    float v = l[e];
    if (v > bv) { bv = v; be = e; }   // strict > : first-max tiebreak like jnp.argmax
  }
  assign[t] = be;
  atomicAdd(&counts[be], 1);
}

// offsets + two tile tables: 256-row tiles (gemm1) and 128-row tiles (gemm2)
__global__ void k_scan(const int* __restrict__ counts,
                       int* __restrict__ offsets,
                       int* __restrict__ t1e, int* __restrict__ t1rb, int* __restrict__ n1,
                       int* __restrict__ t2e, int* __restrict__ t2rb, int* __restrict__ n2) {
  if (threadIdx.x == 0) {
    int acc = 0, a1 = 0, a2 = 0;
    for (int e = 0; e < NEXP; ++e) {
      offsets[e] = acc;
      int c = counts[e];
      acc += c;
      int t1 = (c + 255) >> 8;
      for (int i = 0; i < t1; ++i) { t1e[a1] = e; t1rb[a1] = i; ++a1; }
      int t2 = (c + 127) >> 7;
      for (int i = 0; i < t2; ++i) { t2e[a2] = e; t2rb[a2] = i; ++a2; }
    }
    n1[0] = a1; n2[0] = a2;
  }
}

__global__ void k_place(const int* __restrict__ assign,
                        const int* __restrict__ offsets,
                        int* __restrict__ cursors,
                        int* __restrict__ perm) {
  int t = blockIdx.x * blockDim.x + threadIdx.x;
  if (t >= T_TOKENS) return;
  int e = assign[t];
  int pos = atomicAdd(&cursors[e], 1);
  perm[offsets[e] + pos] = t;
}

// gather tokens into bucket order, cast fp32 -> bf16
__global__ void k_gather_x(const float* __restrict__ x,
                           const int* __restrict__ perm,
                           unsigned short* __restrict__ xg) {
  int idx = blockIdx.x * blockDim.x + threadIdx.x;   // over T*D/4
  int slot = idx / (DDIM / 4);
  int c4 = idx - slot * (DDIM / 4);
  int tok = perm[slot];
  float4 v = ((const float4*)(x + (size_t)tok * DDIM))[c4];
  ushort4 o;
  o.x = f2bf(v.x); o.y = f2bf(v.y); o.z = f2bf(v.z); o.w = f2bf(v.w);
  ((ushort4*)(xg + (size_t)slot * DDIM))[c4] = o;
}

__global__ void k_cast(const float* __restrict__ src,
                       unsigned short* __restrict__ dst, int n4) {
  int i = blockIdx.x * blockDim.x + threadIdx.x;
  if (i >= n4) return;
  float4 v = ((const float4*)src)[i];
  ushort4 o;
  o.x = f2bf(v.x); o.y = f2bf(v.y); o.z = f2bf(v.z); o.w = f2bf(v.w);
  ((ushort4*)dst)[i] = o;
}

__device__ __forceinline__ void glds(const unsigned short* g, unsigned short* l) {
  __builtin_amdgcn_global_load_lds(
      (const __attribute__((address_space(1))) void*)g,
      (__attribute__((address_space(3))) void*)l, 16, 0, 0);
}

// Grouped GEMM, 8-phase schedule (T2+T3+T4+T5):
//  - 8 waves (512 thr), wave grid 2(M) x 4(N), wave output (MW*16) x 64.
//  - FIRST: BM=256 (MW=8), 2 phases/slice; else BM=128 (MW=4), 1 phase/slice.
//  - ring of 4 BK=32 slices in LDS, prefetch distance 3, counted vmcnt (never 0).
//  - per phase: ds_read frags -> issue glds -> barrier -> lgkmcnt(0)+sched_barrier
//    -> setprio(1) 16xMFMA setprio(0) -> barrier.
//  - XOR k-chunk swizzle both-sides (pre-swizzled global src + swizzled ds_read):
//    LDS position p of row r holds global k-chunk p ^ ((r>>1)&3) -> b128 reads
//    conflict-free (was 8-way, 1.78e7 conflicts/dispatch).
template<bool FIRST>
__launch_bounds__(512, 2)
__global__ void k_gemm(const unsigned short* __restrict__ Ap,
                       const unsigned short* __restrict__ Bw,
                       unsigned short* __restrict__ Hout,
                       float* __restrict__ Out,
                       const int* __restrict__ offsets,
                       const int* __restrict__ counts,
                       const int* __restrict__ perm,
                       const int* __restrict__ tile_e,
                       const int* __restrict__ tile_rb,
                       const int* __restrict__ ntiles) {
  constexpr int K   = FIRST ? DDIM : FDIM;   // 2048 : 4096
  constexpr int N   = FIRST ? FDIM : DDIM;   // 4096 : 2048
  constexpr int MW  = FIRST ? 8 : 4;         // m-fragments per wave
  constexpr int BM  = MW * 32;               // 256 : 128
  constexpr int NS  = K / 32;                // 64 : 128  (both %4 == 0)
  constexpr int RA  = MW / 4;                // A staging rounds: 2 : 1
  constexpr int ASL = BM * 32;               // A slice shorts
  constexpr int BSL = 256 * 32;              // B slice shorts

  const int ty = blockIdx.y;
  if (ty >= ntiles[0]) return;
  const int e   = tile_e[ty];
  const int rb  = tile_rb[ty] * BM;
  const int off = offsets[e];
  const int Me  = counts[e];
  const int cb  = blockIdx.x << 8;           // 256 output cols per block

  extern __shared__ unsigned short sm[];
  unsigned short* At = sm;                   // 4 * ASL shorts
  unsigned short* Bt = sm + 4 * ASL;         // 4 * BSL shorts

  const int tid  = threadIdx.x;
  const int wave = tid >> 6;
  const int lane = tid & 63;
  const int wr   = wave >> 2;                // 0..1  (M)
  const int wc   = wave & 3;                 // 0..3  (N)

  // ---- staging map: thread -> (row = r*128 + tid>>2, k-chunk kd) with source
  // pre-swizzle kd = (tid&3) ^ ((tid>>3)&3)  (== (pos) ^ ((row>>1)&3))
  const int tq  = tid >> 2;
  const int kd8 = (((tid & 3) ^ ((tid >> 3) & 3)) << 3);

  const unsigned short* gA[RA];
#pragma unroll
  for (int r = 0; r < RA; ++r) {
    int ar = rb + r * 128 + tq;
    if (ar >= Me) ar = Me - 1;               // clamp ragged M; masked in epilogue
    gA[r] = Ap + (size_t)(off + ar) * K + kd8;
  }
  const unsigned short* gB[2];
#pragma unroll
  for (int r = 0; r < 2; ++r)
    gB[r] = Bw + (size_t)e * N * K + (size_t)(cb + r * 128 + tq) * K + kd8;

  // wave-uniform LDS stage destination bases (glds adds lane*16B itself)
  const int dlo = (wave * 16) * 32;
  const int dhi = dlo + 128 * 32;

  // ---- prologue: issue slices 0,1,2 (oldest-first), wait slice 0 landed
#pragma unroll
  for (int s = 0; s < 3; ++s) {
#pragma unroll
    for (int r = 0; r < RA; ++r)
      glds(gA[r] + s * 32, At + s * ASL + dlo + r * (128 * 32));
#pragma unroll
    for (int r = 0; r < 2; ++r)
      glds(gB[r] + s * 32, Bt + s * BSL + dlo + r * (128 * 32));
  }
  if constexpr (MW == 8) { asm volatile("s_waitcnt vmcnt(8)" ::: "memory"); }
  else                   { asm volatile("s_waitcnt vmcnt(6)" ::: "memory"); }
  __builtin_amdgcn_s_barrier();
  asm volatile("" ::: "memory");   // keep ds_reads from hoisting above the barrier

  // ---- read-side fragment offsets (shorts), swizzled k-chunk
  const int kswz8 = (((lane >> 4) ^ ((lane >> 1) & 3)) << 3);
  const int aoff  = (wr * (BM / 2) + (lane & 15)) * 32 + kswz8;
  const int boff  = (wc * 64 + (lane & 15)) * 32 + kswz8;

  f32x4 acc[MW][4] = {};

  for (int ks = 0; ks < NS; ++ks) {
    const int cur = ks & 3;
    const int pre = (ks + 3) & 3;
    int ka = ks + 3; if (ka >= NS) ka -= NS;   // dummy wrap keeps vmcnt invariant
    const int ko = ka * 32;
    const unsigned short* Ac = At + cur * ASL + aoff;
    const unsigned short* Bc = Bt + cur * BSL + boff;
    unsigned short* Aw = At + pre * ASL;
    unsigned short* Bp = Bt + pre * BSL;

    bf16x8 af[MW], bf[4];
    if constexpr (MW == 8) {
      // ---- phase A: bf[0..3] + af[0..3], stage A of slice ks+3
#pragma unroll
      for (int n = 0; n < 4; ++n) bf[n] = *(const bf16x8*)(Bc + n * 512);
#pragma unroll
      for (int m = 0; m < 4; ++m) af[m] = *(const bf16x8*)(Ac + m * 512);
      glds(gA[0] + ko, Aw + dlo);
      glds(gA[1] + ko, Aw + dhi);
      __builtin_amdgcn_s_barrier();
      asm volatile("s_waitcnt lgkmcnt(0)" ::: "memory");
      __builtin_amdgcn_sched_barrier(0);
      __builtin_amdgcn_s_setprio(1);
#pragma unroll
      for (int m = 0; m < 4; ++m)
#pragma unroll
        for (int n = 0; n < 4; ++n)
          acc[m][n] = __builtin_amdgcn_mfma_f32_16x16x32_bf16(af[m], bf[n], acc[m][n], 0, 0, 0);
      __builtin_amdgcn_s_setprio(0);
      __builtin_amdgcn_s_barrier();
      // ---- phase B: af[4..7], stage B of slice ks+3, counted vmcnt
#pragma unroll
      for (int m = 4; m < 8; ++m) af[m] = *(const bf16x8*)(Ac + m * 512);
      glds(gB[0] + ko, Bp + dlo);
      glds(gB[1] + ko, Bp + dhi);
      asm volatile("s_waitcnt vmcnt(8)" ::: "memory");   // slice ks+1 landed; ks+2,ks+3 in flight
      __builtin_amdgcn_s_barrier();
      asm volatile("s_waitcnt lgkmcnt(0)" ::: "memory");
      __builtin_amdgcn_sched_barrier(0);
      __builtin_amdgcn_s_setprio(1);
#pragma unroll
      for (int m = 4; m < 8; ++m)
#pragma unroll
        for (int n = 0; n < 4; ++n)
          acc[m][n] = __builtin_amdgcn_mfma_f32_16x16x32_bf16(af[m], bf[n], acc[m][n], 0, 0, 0);
      __builtin_amdgcn_s_setprio(0);
      __builtin_amdgcn_s_barrier();
    } else {
      // ---- single phase: bf[0..3] + af[0..3], stage all of slice ks+3
#pragma unroll
      for (int n = 0; n < 4; ++n) bf[n] = *(const bf16x8*)(Bc + n * 512);
#pragma unroll
      for (int m = 0; m < 4; ++m) af[m] = *(const bf16x8*)(Ac + m * 512);
      glds(gA[0] + ko, Aw + dlo);
      glds(gB[0] + ko, Bp + dlo);
      glds(gB[1] + ko, Bp + dhi);
      asm volatile("s_waitcnt vmcnt(6)" ::: "memory");   // slice ks+1 landed
      __builtin_amdgcn_s_barrier();
      asm volatile("s_waitcnt lgkmcnt(0)" ::: "memory");
      __builtin_amdgcn_sched_barrier(0);
      __builtin_amdgcn_s_setprio(1);
#pragma unroll
      for (int m = 0; m < 4; ++m)
#pragma unroll
        for (int n = 0; n < 4; ++n)
          acc[m][n] = __builtin_amdgcn_mfma_f32_16x16x32_bf16(af[m], bf[n], acc[m][n], 0, 0, 0);
      __builtin_amdgcn_s_setprio(0);
      __builtin_amdgcn_s_barrier();
    }
  }

  // ---- epilogue: C/D layout col = lane&15, row = (lane>>4)*4 + reg
  const int ccol = lane & 15;
  const int cr0 = (lane >> 4) * 4;
  const int colbase = cb + wc * 64;
#pragma unroll
  for (int i = 0; i < MW; ++i) {
#pragma unroll
    for (int r = 0; r < 4; ++r) {
      int row = rb + wr * (BM / 2) + i * 16 + cr0 + r;
      if (row < Me) {
        if constexpr (FIRST) {
          unsigned short* hrow = Hout + (size_t)(off + row) * N;
#pragma unroll
          for (int j = 0; j < 4; ++j) {
            float v = acc[i][j][r];
            float s = v / (1.0f + __expf(-v));   // silu
            hrow[colbase + j * 16 + ccol] = f2bf(s);
          }
        } else {
          int tok = perm[off + row];
          float* orow = Out + (size_t)tok * N;
#pragma unroll
          for (int j = 0; j < 4; ++j)
            orow[colbase + j * 16 + ccol] = acc[i][j][r];
        }
      }
    }
  }
}

extern "C" void kernel_launch(void* const* d_in, const int* in_sizes, int n_in,
                              void* d_out, int out_size, void* d_ws, size_t ws_size,
                              hipStream_t stream) {
  const float* x      = (const float*)d_in[0];   // [T, D] fp32
  const float* logits = (const float*)d_in[1];   // [T, E] fp32
  const float* w1     = (const float*)d_in[2];   // [E, F, D] fp32
  const float* w2     = (const float*)d_in[3];   // [E, D, F] fp32
  float* out = (float*)d_out;                    // [T, D] fp32

  char* ws = (char*)d_ws;
  int* counts  = (int*)(ws + 0);
  int* offsets = (int*)(ws + 64);
  int* cursors = (int*)(ws + 128);
  int* t1e  = (int*)(ws + 256);    // 40 ints
  int* t1rb = (int*)(ws + 512);    // 40 ints
  int* n1   = (int*)(ws + 768);
  int* t2e  = (int*)(ws + 1024);   // 72 ints
  int* t2rb = (int*)(ws + 1536);   // 72 ints
  int* n2   = (int*)(ws + 1856);
  int* assign  = (int*)(ws + 4096);
  int* perm    = (int*)(ws + 4096 + T_TOKENS * 4);
  size_t p = 4096 + (size_t)2 * T_TOKENS * 4;
  p = (p + 255) & ~(size_t)255;
  unsigned short* Xg  = (unsigned short*)(ws + p); p += (size_t)T_TOKENS * DDIM * 2;
  unsigned short* W1b = (unsigned short*)(ws + p); p += (size_t)NEXP * FDIM * DDIM * 2;
  unsigned short* W2b = (unsigned short*)(ws + p); p += (size_t)NEXP * DDIM * FDIM * 2;
  unsigned short* Hb  = (unsigned short*)(ws + p); p += (size_t)T_TOKENS * FDIM * 2;
  if (ws_size < p) return;  // ~369 MB required

  // opt-in to >64KB dynamic LDS (128 KiB gemm1 / 96 KiB gemm2)
  hipFuncSetAttribute(reinterpret_cast<const void*>(k_gemm<true>),
                      hipFuncAttributeMaxDynamicSharedMemorySize, 131072);
  hipFuncSetAttribute(reinterpret_cast<const void*>(k_gemm<false>),
                      hipFuncAttributeMaxDynamicSharedMemorySize, 131072);

  hipMemsetAsync(ws, 0, 4096, stream);  // counts + cursors + tables
  k_assign<<<T_TOKENS / 256, 256, 0, stream>>>(logits, assign, counts);
  k_scan<<<1, 64, 0, stream>>>(counts, offsets, t1e, t1rb, n1, t2e, t2rb, n2);
  k_place<<<T_TOKENS / 256, 256, 0, stream>>>(assign, offsets, cursors, perm);
  k_gather_x<<<(T_TOKENS * (DDIM / 4)) / 256, 256, 0, stream>>>(x, perm, Xg);
  int n4 = NEXP * FDIM * (DDIM / 4);
  k_cast<<<n4 / 256, 256, 0, stream>>>(w1, W1b, n4);
  k_cast<<<n4 / 256, 256, 0, stream>>>(w2, W2b, n4);
  k_gemm<true><<<dim3(FDIM / 256, MAXT1), 512, 131072, stream>>>(
      Xg, W1b, Hb, nullptr, offsets, counts, perm, t1e, t1rb, n1);
  k_gemm<false><<<dim3(DDIM / 256, MAXT2), 512, 98304, stream>>>(
      Hb, W2b, nullptr, out, offsets, counts, perm, t2e, t2rb, n2);
}